// Round 9
// baseline (49.794 us; speedup 1.0000x reference)
//
#include <hip/hip_runtime.h>
#include <hip/hip_bf16.h>

// Linear-chain CRF NLL: out[b] = logZ(b) - gold(b).
//
// Round 9 = round 8 (register-resident multi-chain scan + fused gold,
// absmax 0.0) with two pure code-motion changes targeting staging MLP:
//  - Af fragment loads moved AFTER the staging barrier: during staging only
//    ~30 VGPRs are live, so the 32 float4 staged loads/thread can pipeline
//    ~16 deep instead of being VGPR-throttled by 64 in-flight Af loads.
//  - gold gathers moved AFTER the scan (em lines L3-resident), overlapping
//    the stitch epilogue instead of draining into the staging barrier.
// Scan core unchanged: S=128 segments x L=8 rows, chains on MFMA B-side,
// acc->B register rename (k-map k=16(2ks+(e>>2))+4g+(e&3)), ee pre-scaled
// 2^-8 bf16 in LDS, v_cvt_pk_bf16_f32 packs, raw v_exp/v_log.

typedef __attribute__((ext_vector_type(8))) short bf16x8;
typedef __attribute__((ext_vector_type(4))) float f32x4;

#define LOG2E 1.44269504088896340736f
#define LN2   0.69314718055994530942f

constexpr int K = 128, T = 1024, NB = 256;
constexpr int NGRP = 8;    // blocks per batch
constexpr int ROWS = 128;  // 16 chains * 8 rows staged per block
constexpr float SCL = 8.0f; // ee pre-scale: 2^-8 per application

__device__ inline unsigned short f2bf(float f) {
    unsigned u = __builtin_bit_cast(unsigned, f);
    u += 0x7FFFu + ((u >> 16) & 1u);   // RNE
    return (unsigned short)(u >> 16);
}
__device__ inline unsigned packbf2(float x, float y) {
    return (unsigned)f2bf(x) | ((unsigned)f2bf(y) << 16);
}
// packed RNE f32x2 -> bf16x2 in one instruction (lo = first arg)
__device__ inline unsigned cvtpk(float lo, float hi) {
    unsigned r;
    asm("v_cvt_pk_bf16_f32 %0, %1, %2" : "=v"(r) : "v"(lo), "v"(hi));
    return r;
}
__device__ inline float bflo(unsigned u) { return __builtin_bit_cast(float, u << 16); }
__device__ inline float bfhi(unsigned u) { return __builtin_bit_cast(float, u & 0xffff0000u); }
__device__ inline float fexp2(float x) { return __builtin_amdgcn_exp2f(x); }
__device__ inline float flog2(float x) { return __builtin_amdgcn_logf(x); }

// A-fragment pack: bp[dir][t][ks][lane][e] = E[k][16t+c] (fwd) / E^T (bwd),
// k = 16*(2ks+(e>>2)) + 4g + (e&3)  (same map the B operand uses in-kernel).
__global__ void bpack_k(const float* __restrict__ tr, unsigned short* __restrict__ bp) {
    int idx = blockIdx.x * 256 + threadIdx.x;   // 0..4095
    int l = idx & 63, ks = (idx >> 6) & 3, t = (idx >> 8) & 7, dir = idx >> 11;
    int c = l & 15, g = l >> 4;
    int n = 16 * t + c;
    unsigned w[4];
#pragma unroll
    for (int j = 0; j < 4; ++j) {
        int e0 = 2 * j, e1 = 2 * j + 1;
        int k0 = 16 * (2 * ks + (e0 >> 2)) + 4 * g + (e0 & 3);
        int k1 = 16 * (2 * ks + (e1 >> 2)) + 4 * g + (e1 & 3);
        float tv0 = dir ? tr[n * K + k0] : tr[k0 * K + n];
        float tv1 = dir ? tr[n * K + k1] : tr[k1 * K + n];
        w[j] = packbf2(fexp2(tv0 * LOG2E), fexp2(tv1 * LOG2E));
    }
    uint4 o; o.x = w[0]; o.y = w[1]; o.z = w[2]; o.w = w[3];
    *(uint4*)(bp + (size_t)idx * 8) = o;
}

__global__ __launch_bounds__(128, 2) void crf_seg(
    const float* __restrict__ em,    // [256][1024][128]
    const float* __restrict__ tr,    // [128][128]
    const float* __restrict__ st,    // [128]
    const float* __restrict__ en,    // [128]
    const int*   __restrict__ tg,    // [256][1024]
    const unsigned short* __restrict__ bp,
    float* __restrict__ bnd_phi,     // [256][8][128]  log phi of chain 15
    float* __restrict__ bnd_psi,     // [256][8][128]  log psi of chain 0
    float* __restrict__ part)        // [256][8] stitch partial - gold partial
{
    const int tid = threadIdx.x;
    const int wv = tid >> 6, l = tid & 63, c = l & 15, g = l >> 4;
    const int b = blockIdx.x >> 3, G = blockIdx.x & 7;

    __shared__ __align__(16) unsigned char eebuf[33024];  // ee bf16, row-skewed
    __shared__ float shLse[16], shCr[16], shG[2];

    // ---- stage ee = exp(em)*2^-8 as bf16, linear tags, row base skewed ----
    // (no other loads in flight: staging float4 loads pipeline ~16 deep)
    // uint2 slot(R,q) = R*32 + (R>>3)*2 + q   (q = tag quad 0..31)
    {
        const float* eb = em + ((size_t)b * T + (size_t)G * ROWS) * K;
        uint2* eev = (uint2*)eebuf;
#pragma unroll 16
        for (int it = 0; it < 32; ++it) {
            int flat = it * 128 + tid;          // 0..4095 float4s
            int R = flat >> 5, q = flat & 31;
            float4 v = ((const float4*)eb)[flat];
            unsigned lo = cvtpk(fexp2(fmaf(v.x, LOG2E, -SCL)), fexp2(fmaf(v.y, LOG2E, -SCL)));
            unsigned hi = cvtpk(fexp2(fmaf(v.z, LOG2E, -SCL)), fexp2(fmaf(v.w, LOG2E, -SCL)));
            eev[R * 32 + (R >> 3) * 2 + q] = make_uint2(lo, hi);
        }
    }
    __syncthreads();

    // ---- A fragments (post-staging: 64 L2-hot loads, drain before 1st MFMA)
    bf16x8 Af[8][4];
    {
        const bf16x8* bpw = (const bf16x8*)bp;
#pragma unroll
        for (int t = 0; t < 8; ++t)
#pragma unroll
            for (int ks = 0; ks < 4; ++ks)
                Af[t][ks] = bpw[((wv * 8 + t) * 4 + ks) * 64 + l];
    }

    const uint2* eev = (const uint2*)eebuf;
    const int rbase = c * 258 + g;   // uint2 index: + i*32 + 4*t

    f32x4 acc[8];
#pragma unroll
    for (int t = 0; t < 8; ++t) { f32x4 o1 = {1.f, 1.f, 1.f, 1.f}; acc[t] = o1; }

#define BUILD_B()                                                      \
    bf16x8 B[4];                                                       \
    _Pragma("unroll")                                                  \
    for (int ks = 0; ks < 4; ++ks) {                                   \
        uint4 bu;                                                      \
        bu.x = cvtpk(acc[2 * ks][0], acc[2 * ks][1]);                  \
        bu.y = cvtpk(acc[2 * ks][2], acc[2 * ks][3]);                  \
        bu.z = cvtpk(acc[2 * ks + 1][0], acc[2 * ks + 1][1]);          \
        bu.w = cvtpk(acc[2 * ks + 1][2], acc[2 * ks + 1][3]);          \
        B[ks] = __builtin_bit_cast(bf16x8, bu);                        \
    }

#define DO_MFMA()                                                      \
    _Pragma("unroll")                                                  \
    for (int t = 0; t < 8; ++t) {                                      \
        f32x4 z = {0.f, 0.f, 0.f, 0.f};                                \
        z = __builtin_amdgcn_mfma_f32_16x16x32_bf16(Af[t][0], B[0], z, 0, 0, 0); \
        z = __builtin_amdgcn_mfma_f32_16x16x32_bf16(Af[t][1], B[1], z, 0, 0, 0); \
        z = __builtin_amdgcn_mfma_f32_16x16x32_bf16(Af[t][2], B[2], z, 0, 0, 0); \
        z = __builtin_amdgcn_mfma_f32_16x16x32_bf16(Af[t][3], B[3], z, 0, 0, 0); \
        acc[t] = z;                                                    \
    }

#define MUL_EE(EC)                                                     \
    _Pragma("unroll")                                                  \
    for (int t = 0; t < 8; ++t) {                                      \
        acc[t][0] *= bflo(EC[t].x);                                    \
        acc[t][1] *= bfhi(EC[t].x);                                    \
        acc[t][2] *= bflo(EC[t].y);                                    \
        acc[t][3] *= bfhi(EC[t].y);                                    \
    }

    if (wv == 0) {
        // fwd: a <- diag(ee_i) * E^T * a, i = 0..7
        uint2 ecur[8];
#pragma unroll
        for (int i = 0; i < 8; ++i) {
#pragma unroll
            for (int t = 0; t < 8; ++t) ecur[t] = eev[rbase + i * 32 + 4 * t];
            BUILD_B()
            DO_MFMA()
            if (G == 0 && i == 0 && c == 0) {   // exact start for segment 0
#pragma unroll
                for (int t = 0; t < 8; ++t)
#pragma unroll
                    for (int r = 0; r < 4; ++r)
                        acc[t][r] = fexp2(st[16 * t + 4 * g + r] * LOG2E);
            }
            MUL_EE(ecur)
        }
    } else {
        // bwd: w <- E * diag(ee_i) * w, i = 7..0
        uint2 ecur[8], enx[8];
#pragma unroll
        for (int t = 0; t < 8; ++t) ecur[t] = eev[rbase + 7 * 32 + 4 * t];
#pragma unroll
        for (int jj = 0; jj < 8; ++jj) {
            MUL_EE(ecur)
            if (jj < 7) {
#pragma unroll
                for (int t = 0; t < 8; ++t) enx[t] = eev[rbase + (6 - jj) * 32 + 4 * t];
            }
            BUILD_B()
            DO_MFMA()
#pragma unroll
            for (int t = 0; t < 8; ++t) ecur[t] = enx[t];
        }
    }
#undef BUILD_B
#undef DO_MFMA
#undef MUL_EE

    // ---- gold gather (post-scan; em fully L3-resident, overlaps epilogue)
    float gev, gtrv, genv;
    {
        const int t = G * ROWS + tid;
        int tgcur = tg[(size_t)b * T + t];
        int tgprev = __shfl_up(tgcur, 1);
        if (l == 0 && t > 0) tgprev = tg[(size_t)b * T + t - 1];
        gev  = em[((size_t)b * T + t) * K + tgcur];
        gtrv = (t == 0) ? st[tgcur] : tr[tgprev * K + tgcur];
        genv = (t == T - 1) ? en[tgcur] : 0.f;
    }

    // ---- epilogue: stitch pieces. True log = log2(linear)*LN2 + 64*LN2. ----
    __syncthreads();                      // scans done; eebuf free to alias
    float* shF = (float*)eebuf;           // [16][132] phi linear
    if (wv == 0) {
        float sum = 0.f;
#pragma unroll
        for (int t = 0; t < 8; ++t)
#pragma unroll
            for (int r = 0; r < 4; ++r) {
                shF[c * 132 + 16 * t + 4 * g + r] = acc[t][r];
                sum += acc[t][r];
            }
        sum += __shfl_xor(sum, 16);
        sum += __shfl_xor(sum, 32);
        if (g == 0) shLse[c] = flog2(sum) + 64.0f;
        if (c == 15) {
#pragma unroll
            for (int t = 0; t < 8; ++t)
#pragma unroll
                for (int r = 0; r < 4; ++r)
                    bnd_phi[((size_t)b * NGRP + G) * K + 16 * t + 4 * g + r] =
                        (flog2(acc[t][r]) + 64.f) * LN2;
        }
    } else if (c == 0) {
#pragma unroll
        for (int t = 0; t < 8; ++t)
#pragma unroll
            for (int r = 0; r < 4; ++r)
                bnd_psi[((size_t)b * NGRP + G) * K + 16 * t + 4 * g + r] =
                    (flog2(acc[t][r]) + 64.f) * LN2;
    }
    __syncthreads();
    if (wv == 1 && c >= 1) {              // cross_c = LSE(psi_c + phi_{c-1})
        float dot = 0.f;
#pragma unroll
        for (int t = 0; t < 8; ++t)
#pragma unroll
            for (int r = 0; r < 4; ++r)
                dot += acc[t][r] * shF[(c - 1) * 132 + 16 * t + 4 * g + r];
        dot += __shfl_xor(dot, 16);
        dot += __shfl_xor(dot, 32);
        if (g == 0) shCr[c] = (flog2(dot) + 128.f) - shLse[c];
    }
    // gold partial: reduce this wave's 64 rows (gather latency hidden above)
    {
        float gd = gtrv + gev + genv;
        gd += __shfl_xor(gd, 1);
        gd += __shfl_xor(gd, 2);
        gd += __shfl_xor(gd, 4);
        gd += __shfl_xor(gd, 8);
        gd += __shfl_xor(gd, 16);
        gd += __shfl_xor(gd, 32);
        if (l == 0) shG[wv] = gd;
    }
    __syncthreads();
    if (tid == 0) {
        float pt = 0.f;
#pragma unroll
        for (int cs = 1; cs < 16; ++cs) pt += shCr[cs];
        if (G > 0) pt -= shLse[0];
        part[b * NGRP + G] = pt * LN2 - (shG[0] + shG[1]);
    }
}

__device__ inline float waveLSE128(float a1, float a2) {
    float mx = fmaxf(a1, a2);
    mx = fmaxf(mx, __shfl_xor(mx, 1));
    mx = fmaxf(mx, __shfl_xor(mx, 2));
    mx = fmaxf(mx, __shfl_xor(mx, 4));
    mx = fmaxf(mx, __shfl_xor(mx, 8));
    mx = fmaxf(mx, __shfl_xor(mx, 16));
    mx = fmaxf(mx, __shfl_xor(mx, 32));
    float sm = fexp2((a1 - mx) * LOG2E) + fexp2((a2 - mx) * LOG2E);
    sm += __shfl_xor(sm, 1);
    sm += __shfl_xor(sm, 2);
    sm += __shfl_xor(sm, 4);
    sm += __shfl_xor(sm, 8);
    sm += __shfl_xor(sm, 16);
    sm += __shfl_xor(sm, 32);
    return mx + flog2(sm) * LN2;
}

// boundary stitch only (gold already folded into part): 256 blocks x 256 thr
__global__ __launch_bounds__(256, 1) void crf_fin(
    const float* __restrict__ en,
    const float* __restrict__ bnd_phi, const float* __restrict__ bnd_psi,
    const float* __restrict__ part, float* __restrict__ out)
{
    const int b = blockIdx.x, tid = threadIdx.x, l = tid & 63, wv = tid >> 6;
    __shared__ float redz[4];

    float z = 0.f;
    for (int tau = wv; tau < 8; tau += 4) {
        float a1, a2;
        if (tau < 7) {
            int Gx = tau + 1;
            a1 = bnd_psi[((size_t)b * NGRP + Gx) * K + l] +
                 bnd_phi[((size_t)b * NGRP + Gx - 1) * K + l];
            a2 = bnd_psi[((size_t)b * NGRP + Gx) * K + 64 + l] +
                 bnd_phi[((size_t)b * NGRP + Gx - 1) * K + 64 + l];
        } else {
            a1 = en[l]      + bnd_phi[((size_t)b * NGRP + 7) * K + l];
            a2 = en[64 + l] + bnd_phi[((size_t)b * NGRP + 7) * K + 64 + l];
        }
        z += waveLSE128(a1, a2);
    }
    if (l == 0) redz[wv] = z;
    __syncthreads();
    if (tid == 0) {
        float ps = 0.f;
#pragma unroll
        for (int Gx = 0; Gx < 8; ++Gx) ps += part[b * NGRP + Gx];
        out[b] = redz[0] + redz[1] + redz[2] + redz[3] + ps;
    }
}

extern "C" void kernel_launch(void* const* d_in, const int* in_sizes, int n_in,
                              void* d_out, int out_size, void* d_ws, size_t ws_size,
                              hipStream_t stream) {
    const float* em = (const float*)d_in[0];
    const float* tr = (const float*)d_in[1];
    const float* st = (const float*)d_in[2];
    const float* en = (const float*)d_in[3];
    const int*   tg = (const int*)d_in[4];
    // d_in[5] = mask: all-true for this problem; unused.

    unsigned short* bp = (unsigned short*)d_ws;               // 64 KB
    float* bnd_phi = (float*)((char*)d_ws + 65536);           // 1 MB
    float* bnd_psi = bnd_phi + (size_t)NB * NGRP * K;         // 1 MB
    float* part    = bnd_psi + (size_t)NB * NGRP * K;         // 8 KB
    float* out = (float*)d_out;

    bpack_k<<<16, 256, 0, stream>>>(tr, bp);
    crf_seg<<<NB * NGRP, 128, 0, stream>>>(em, tr, st, en, tg, bp, bnd_phi, bnd_psi, part);
    crf_fin<<<NB, 256, 0, stream>>>(en, bnd_phi, bnd_psi, part, out);
}

// Round 10
// 49.758 us; speedup vs baseline: 1.0007x; 1.0007x over previous
//
#include <hip/hip_runtime.h>
#include <hip/hip_bf16.h>

// Linear-chain CRF NLL: out[b] = logZ(b) - gold(b).
//
// Round 10 = round 8 base (best so far, 47.9 us) + latency package:
//  - MFMA chain-break: 2 independent 2-chains + f32x4 add (dep depth 4->2).
//  - ee LDS layout: XOR swizzle slot = R*32 + (q ^ 2*(R>>3)) -> 2 lanes/bank
//    (conflict-free), no pad; reader chain c owns rows c*8+i so the write-side
//    swizzle key (R>>3) equals the reader's c.
//  - s_setprio(1) around MFMA cluster (waves are phase-diverse: fwd vs bwd).
//  - fwd step-0 B operand is the constant bf16(1.0) pattern (acc==1 exactly).
//  - vectorized MUL_EE.
// Core unchanged: S=128 segments x L=8 rows, chains on MFMA B-side, acc->B
// register rename (k-map k=16(2ks+(e>>2))+4g+(e&3)), ee pre-scaled 2^-8 bf16,
// gold fused, stitch via in-block dots + tiny crf_fin.

typedef __attribute__((ext_vector_type(8))) short bf16x8;
typedef __attribute__((ext_vector_type(4))) float f32x4;

#define LOG2E 1.44269504088896340736f
#define LN2   0.69314718055994530942f

constexpr int K = 128, T = 1024, NB = 256;
constexpr int NGRP = 8;    // blocks per batch
constexpr int ROWS = 128;  // 16 chains * 8 rows staged per block
constexpr float SCL = 8.0f; // ee pre-scale: 2^-8 per application

__device__ inline unsigned short f2bf(float f) {
    unsigned u = __builtin_bit_cast(unsigned, f);
    u += 0x7FFFu + ((u >> 16) & 1u);   // RNE
    return (unsigned short)(u >> 16);
}
__device__ inline unsigned packbf2(float x, float y) {
    return (unsigned)f2bf(x) | ((unsigned)f2bf(y) << 16);
}
// packed RNE f32x2 -> bf16x2 in one instruction (lo = first arg)
__device__ inline unsigned cvtpk(float lo, float hi) {
    unsigned r;
    asm("v_cvt_pk_bf16_f32 %0, %1, %2" : "=v"(r) : "v"(lo), "v"(hi));
    return r;
}
__device__ inline float bflo(unsigned u) { return __builtin_bit_cast(float, u << 16); }
__device__ inline float bfhi(unsigned u) { return __builtin_bit_cast(float, u & 0xffff0000u); }
__device__ inline float fexp2(float x) { return __builtin_amdgcn_exp2f(x); }
__device__ inline float flog2(float x) { return __builtin_amdgcn_logf(x); }

// A-fragment pack: bp[dir][t][ks][lane][e] = E[k][16t+c] (fwd) / E^T (bwd),
// k = 16*(2ks+(e>>2)) + 4g + (e&3)  (same map the B operand uses in-kernel).
__global__ void bpack_k(const float* __restrict__ tr, unsigned short* __restrict__ bp) {
    int idx = blockIdx.x * 256 + threadIdx.x;   // 0..4095
    int l = idx & 63, ks = (idx >> 6) & 3, t = (idx >> 8) & 7, dir = idx >> 11;
    int c = l & 15, g = l >> 4;
    int n = 16 * t + c;
    unsigned w[4];
#pragma unroll
    for (int j = 0; j < 4; ++j) {
        int e0 = 2 * j, e1 = 2 * j + 1;
        int k0 = 16 * (2 * ks + (e0 >> 2)) + 4 * g + (e0 & 3);
        int k1 = 16 * (2 * ks + (e1 >> 2)) + 4 * g + (e1 & 3);
        float tv0 = dir ? tr[n * K + k0] : tr[k0 * K + n];
        float tv1 = dir ? tr[n * K + k1] : tr[k1 * K + n];
        w[j] = packbf2(fexp2(tv0 * LOG2E), fexp2(tv1 * LOG2E));
    }
    uint4 o; o.x = w[0]; o.y = w[1]; o.z = w[2]; o.w = w[3];
    *(uint4*)(bp + (size_t)idx * 8) = o;
}

__global__ __launch_bounds__(128, 2) void crf_seg(
    const float* __restrict__ em,    // [256][1024][128]
    const float* __restrict__ tr,    // [128][128]
    const float* __restrict__ st,    // [128]
    const float* __restrict__ en,    // [128]
    const int*   __restrict__ tg,    // [256][1024]
    const unsigned short* __restrict__ bp,
    float* __restrict__ bnd_phi,     // [256][8][128]  log phi of chain 15
    float* __restrict__ bnd_psi,     // [256][8][128]  log psi of chain 0
    float* __restrict__ part)        // [256][8] stitch partial - gold partial
{
    const int tid = threadIdx.x;
    const int wv = tid >> 6, l = tid & 63, c = l & 15, g = l >> 4;
    const int b = blockIdx.x >> 3, G = blockIdx.x & 7;

    __shared__ __align__(16) unsigned char eebuf[32768];  // ee bf16, XOR-swizzled
    __shared__ float shLse[16], shCr[16], shG[2];

    // ---- A fragments ----
    bf16x8 Af[8][4];
    {
        const bf16x8* bpw = (const bf16x8*)bp;
#pragma unroll
        for (int t = 0; t < 8; ++t)
#pragma unroll
            for (int ks = 0; ks < 4; ++ks)
                Af[t][ks] = bpw[((wv * 8 + t) * 4 + ks) * 64 + l];
    }

    // ---- stage ee = exp(em)*2^-8 as bf16 ----
    // uint2 slot(R, q) = R*32 + (q ^ 2*(R>>3));  q = tag quad 0..31.
    // Reader chain c owns rows R = c*8+i -> R>>3 == c, so read addr
    // slot = R*32 + ((4t+g) ^ 2c): 2 lanes/bank (conflict-free).
    {
        const float* eb = em + ((size_t)b * T + (size_t)G * ROWS) * K;
        uint2* eev = (uint2*)eebuf;
#pragma unroll 16
        for (int it = 0; it < 32; ++it) {
            int flat = it * 128 + tid;          // 0..4095 float4s
            int R = flat >> 5, q = flat & 31;
            float4 v = ((const float4*)eb)[flat];
            unsigned lo = cvtpk(fexp2(fmaf(v.x, LOG2E, -SCL)), fexp2(fmaf(v.y, LOG2E, -SCL)));
            unsigned hi = cvtpk(fexp2(fmaf(v.z, LOG2E, -SCL)), fexp2(fmaf(v.w, LOG2E, -SCL)));
            eev[R * 32 + (q ^ ((R >> 3) << 1))] = make_uint2(lo, hi);
        }
    }

    // ---- gold gather for this block's 128 rows (issued pre-barrier; waits
    //      sink past the scan). Row t = G*128 + tid.
    float gev, gtrv, genv;
    {
        const int t = G * ROWS + tid;
        int tgcur = tg[(size_t)b * T + t];
        int tgprev = __shfl_up(tgcur, 1);
        if (l == 0 && t > 0) tgprev = tg[(size_t)b * T + t - 1];
        gev  = em[((size_t)b * T + t) * K + tgcur];
        gtrv = (t == 0) ? st[tgcur] : tr[tgprev * K + tgcur];
        genv = (t == T - 1) ? en[tgcur] : 0.f;
    }
    __syncthreads();

    const uint2* eev = (const uint2*)eebuf;
    const int twoc = c << 1;

    f32x4 acc[8];
#pragma unroll
    for (int t = 0; t < 8; ++t) { f32x4 o1 = {1.f, 1.f, 1.f, 1.f}; acc[t] = o1; }

#define BUILD_B()                                                      \
    _Pragma("unroll")                                                  \
    for (int ks = 0; ks < 4; ++ks) {                                   \
        uint4 bu;                                                      \
        bu.x = cvtpk(acc[2 * ks][0], acc[2 * ks][1]);                  \
        bu.y = cvtpk(acc[2 * ks][2], acc[2 * ks][3]);                  \
        bu.z = cvtpk(acc[2 * ks + 1][0], acc[2 * ks + 1][1]);          \
        bu.w = cvtpk(acc[2 * ks + 1][2], acc[2 * ks + 1][3]);          \
        B[ks] = __builtin_bit_cast(bf16x8, bu);                        \
    }

#define DO_MFMA()                                                      \
    __builtin_amdgcn_s_setprio(1);                                     \
    _Pragma("unroll")                                                  \
    for (int t = 0; t < 8; ++t) {                                      \
        f32x4 z0 = {0.f, 0.f, 0.f, 0.f}, z1 = {0.f, 0.f, 0.f, 0.f};   \
        z0 = __builtin_amdgcn_mfma_f32_16x16x32_bf16(Af[t][0], B[0], z0, 0, 0, 0); \
        z0 = __builtin_amdgcn_mfma_f32_16x16x32_bf16(Af[t][1], B[1], z0, 0, 0, 0); \
        z1 = __builtin_amdgcn_mfma_f32_16x16x32_bf16(Af[t][2], B[2], z1, 0, 0, 0); \
        z1 = __builtin_amdgcn_mfma_f32_16x16x32_bf16(Af[t][3], B[3], z1, 0, 0, 0); \
        acc[t] = z0 + z1;                                              \
    }                                                                  \
    __builtin_amdgcn_s_setprio(0);

#define MUL_EE(EC)                                                     \
    _Pragma("unroll")                                                  \
    for (int t = 0; t < 8; ++t) {                                      \
        f32x4 ev;                                                      \
        ev[0] = bflo(EC[t].x); ev[1] = bfhi(EC[t].x);                  \
        ev[2] = bflo(EC[t].y); ev[3] = bfhi(EC[t].y);                  \
        acc[t] *= ev;                                                  \
    }

    if (wv == 0) {
        // fwd: a <- diag(ee_i) * E^T * a, i = 0..7
        bf16x8 B[4];
        uint2 ecur[8];
#pragma unroll
        for (int i = 0; i < 8; ++i) {
            const int ro = (c * 8 + i) * 32;
#pragma unroll
            for (int t = 0; t < 8; ++t) ecur[t] = eev[ro + ((4 * t + g) ^ twoc)];
            if (i == 0) {
                // acc == 1 exactly: cvtpk(1,1) == 0x3F803F80
                uint4 bu; bu.x = bu.y = bu.z = bu.w = 0x3F803F80u;
#pragma unroll
                for (int ks = 0; ks < 4; ++ks) B[ks] = __builtin_bit_cast(bf16x8, bu);
            } else {
                BUILD_B()
            }
            DO_MFMA()
            if (G == 0 && i == 0 && c == 0) {   // exact start for segment 0
#pragma unroll
                for (int t = 0; t < 8; ++t)
#pragma unroll
                    for (int r = 0; r < 4; ++r)
                        acc[t][r] = fexp2(st[16 * t + 4 * g + r] * LOG2E);
            }
            MUL_EE(ecur)
        }
    } else {
        // bwd: w <- E * diag(ee_i) * w, i = 7..0
        bf16x8 B[4];
        uint2 ecur[8], enx[8];
        {
            const int ro = (c * 8 + 7) * 32;
#pragma unroll
            for (int t = 0; t < 8; ++t) ecur[t] = eev[ro + ((4 * t + g) ^ twoc)];
        }
#pragma unroll
        for (int jj = 0; jj < 8; ++jj) {
            MUL_EE(ecur)
            if (jj < 7) {
                const int ro = (c * 8 + 6 - jj) * 32;
#pragma unroll
                for (int t = 0; t < 8; ++t) enx[t] = eev[ro + ((4 * t + g) ^ twoc)];
            }
            BUILD_B()
            DO_MFMA()
#pragma unroll
            for (int t = 0; t < 8; ++t) ecur[t] = enx[t];
        }
    }
#undef BUILD_B
#undef DO_MFMA
#undef MUL_EE

    // ---- gold partial: reduce this wave's 64 rows ----
    {
        float gd = gtrv + gev + genv;
        gd += __shfl_xor(gd, 1);
        gd += __shfl_xor(gd, 2);
        gd += __shfl_xor(gd, 4);
        gd += __shfl_xor(gd, 8);
        gd += __shfl_xor(gd, 16);
        gd += __shfl_xor(gd, 32);
        if (l == 0) shG[wv] = gd;
    }

    // ---- epilogue: stitch pieces. True log = log2(linear)*LN2 + 64*LN2. ----
    __syncthreads();                      // scans done; eebuf free to alias
    float* shF = (float*)eebuf;           // [16][132] phi linear (8448 B)
    if (wv == 0) {
        float sum = 0.f;
#pragma unroll
        for (int t = 0; t < 8; ++t)
#pragma unroll
            for (int r = 0; r < 4; ++r) {
                shF[c * 132 + 16 * t + 4 * g + r] = acc[t][r];
                sum += acc[t][r];
            }
        sum += __shfl_xor(sum, 16);
        sum += __shfl_xor(sum, 32);
        if (g == 0) shLse[c] = flog2(sum) + 64.0f;
        if (c == 15) {
#pragma unroll
            for (int t = 0; t < 8; ++t)
#pragma unroll
                for (int r = 0; r < 4; ++r)
                    bnd_phi[((size_t)b * NGRP + G) * K + 16 * t + 4 * g + r] =
                        (flog2(acc[t][r]) + 64.f) * LN2;
        }
    } else if (c == 0) {
#pragma unroll
        for (int t = 0; t < 8; ++t)
#pragma unroll
            for (int r = 0; r < 4; ++r)
                bnd_psi[((size_t)b * NGRP + G) * K + 16 * t + 4 * g + r] =
                    (flog2(acc[t][r]) + 64.f) * LN2;
    }
    __syncthreads();
    if (wv == 1 && c >= 1) {              // cross_c = LSE(psi_c + phi_{c-1})
        float dot = 0.f;
#pragma unroll
        for (int t = 0; t < 8; ++t)
#pragma unroll
            for (int r = 0; r < 4; ++r)
                dot += acc[t][r] * shF[(c - 1) * 132 + 16 * t + 4 * g + r];
        dot += __shfl_xor(dot, 16);
        dot += __shfl_xor(dot, 32);
        if (g == 0) shCr[c] = (flog2(dot) + 128.f) - shLse[c];
    }
    __syncthreads();
    if (tid == 0) {
        float pt = 0.f;
#pragma unroll
        for (int cs = 1; cs < 16; ++cs) pt += shCr[cs];
        if (G > 0) pt -= shLse[0];
        part[b * NGRP + G] = pt * LN2 - (shG[0] + shG[1]);
    }
}

__device__ inline float waveLSE128(float a1, float a2) {
    float mx = fmaxf(a1, a2);
    mx = fmaxf(mx, __shfl_xor(mx, 1));
    mx = fmaxf(mx, __shfl_xor(mx, 2));
    mx = fmaxf(mx, __shfl_xor(mx, 4));
    mx = fmaxf(mx, __shfl_xor(mx, 8));
    mx = fmaxf(mx, __shfl_xor(mx, 16));
    mx = fmaxf(mx, __shfl_xor(mx, 32));
    float sm = fexp2((a1 - mx) * LOG2E) + fexp2((a2 - mx) * LOG2E);
    sm += __shfl_xor(sm, 1);
    sm += __shfl_xor(sm, 2);
    sm += __shfl_xor(sm, 4);
    sm += __shfl_xor(sm, 8);
    sm += __shfl_xor(sm, 16);
    sm += __shfl_xor(sm, 32);
    return mx + flog2(sm) * LN2;
}

// boundary stitch only (gold already folded into part): 256 blocks x 256 thr
__global__ __launch_bounds__(256, 1) void crf_fin(
    const float* __restrict__ en,
    const float* __restrict__ bnd_phi, const float* __restrict__ bnd_psi,
    const float* __restrict__ part, float* __restrict__ out)
{
    const int b = blockIdx.x, tid = threadIdx.x, l = tid & 63, wv = tid >> 6;
    __shared__ float redz[4];

    float z = 0.f;
    for (int tau = wv; tau < 8; tau += 4) {
        float a1, a2;
        if (tau < 7) {
            int Gx = tau + 1;
            a1 = bnd_psi[((size_t)b * NGRP + Gx) * K + l] +
                 bnd_phi[((size_t)b * NGRP + Gx - 1) * K + l];
            a2 = bnd_psi[((size_t)b * NGRP + Gx) * K + 64 + l] +
                 bnd_phi[((size_t)b * NGRP + Gx - 1) * K + 64 + l];
        } else {
            a1 = en[l]      + bnd_phi[((size_t)b * NGRP + 7) * K + l];
            a2 = en[64 + l] + bnd_phi[((size_t)b * NGRP + 7) * K + 64 + l];
        }
        z += waveLSE128(a1, a2);
    }
    if (l == 0) redz[wv] = z;
    __syncthreads();
    if (tid == 0) {
        float ps = 0.f;
#pragma unroll
        for (int Gx = 0; Gx < 8; ++Gx) ps += part[b * NGRP + Gx];
        out[b] = redz[0] + redz[1] + redz[2] + redz[3] + ps;
    }
}

extern "C" void kernel_launch(void* const* d_in, const int* in_sizes, int n_in,
                              void* d_out, int out_size, void* d_ws, size_t ws_size,
                              hipStream_t stream) {
    const float* em = (const float*)d_in[0];
    const float* tr = (const float*)d_in[1];
    const float* st = (const float*)d_in[2];
    const float* en = (const float*)d_in[3];
    const int*   tg = (const int*)d_in[4];
    // d_in[5] = mask: all-true for this problem; unused.

    unsigned short* bp = (unsigned short*)d_ws;               // 64 KB
    float* bnd_phi = (float*)((char*)d_ws + 65536);           // 1 MB
    float* bnd_psi = bnd_phi + (size_t)NB * NGRP * K;         // 1 MB
    float* part    = bnd_psi + (size_t)NB * NGRP * K;         // 8 KB
    float* out = (float*)d_out;

    bpack_k<<<16, 256, 0, stream>>>(tr, bp);
    crf_seg<<<NB * NGRP, 128, 0, stream>>>(em, tr, st, en, tg, bp, bnd_phi, bnd_psi, part);
    crf_fin<<<NB, 256, 0, stream>>>(en, bnd_phi, bnd_psi, part, out);
}